// Round 1
// baseline (785.864 us; speedup 1.0000x reference)
//
#include <hip/hip_runtime.h>

// Problem constants
#define CDIM 1152
#define NDIS 30
#define NPROJ 60           // 30 score rows + 30 head rows
#define NVOX (64*64*64)    // 262144
#define NBLK (NVOX/256)    // 1024 blocks for proj/soft kernels

// Workspace layout (float offsets)
#define WT_OFF 0                                 // W_t [1152][64] packed (rows 0..29 score_w, 30..59 head_w, 60..63 zero)
#define S_OFF  (CDIM*64)                         // 73728: S [60][NVOX] projections
#define SMAX_OFF (S_OFF + NPROJ*NVOX)            // 32 uints (encoded f32 max per disease)
#define INVTAU_OFF (SMAX_OFF + 32)               // 32 floats
#define PNUM_OFF (INVTAU_OFF + 32)               // [30][4096] per-wave partial sums of e*h
#define PDEN_OFF (PNUM_OFF + NDIS*4096)          // [30][4096] per-wave partial sums of e
// total = PDEN_OFF + 30*4096 = 16,048,192 floats ~= 61.2 MiB

// Order-preserving float<->uint encoding so atomicMax(uint) == float max (deterministic).
__device__ inline unsigned encf(float f) {
    unsigned u = __float_as_uint(f);
    return (u & 0x80000000u) ? ~u : (u | 0x80000000u);
}
__device__ inline float decf(unsigned u) {
    return __uint_as_float((u & 0x80000000u) ? (u & 0x7fffffffu) : ~u);
}

// K0: pack weights transposed [c][d] for uniform coalesced reads, prep invtau, init smax.
__global__ void k_prep(const float* __restrict__ score_w,
                       const float* __restrict__ head_w,
                       const float* __restrict__ temp_logit,
                       float* __restrict__ ws) {
    float* wt = ws + WT_OFF;
    const int total = CDIM * 64;
    for (int i = blockIdx.x * blockDim.x + threadIdx.x; i < total; i += gridDim.x * blockDim.x) {
        int c = i >> 6, d = i & 63;
        float v = 0.f;
        if (d < NDIS)       v = score_w[d * CDIM + c];
        else if (d < NPROJ) v = head_w[(d - NDIS) * CDIM + c];
        wt[i] = v;
    }
    if (blockIdx.x == 0 && threadIdx.x < NDIS) {
        float t = temp_logit[threadIdx.x];
        float sig = 1.f / (1.f + expf(-t));
        float tau = 0.2f + 1.8f * sig;
        ws[INVTAU_OFF + threadIdx.x] = 1.f / tau;
        // -inf encoded
        ((unsigned*)(ws + SMAX_OFF))[threadIdx.x] = encf(__uint_as_float(0xFF800000u));
    }
}

// K1 (hot): per-thread n, 60 f32 accumulators over c. One coalesced activ read per c,
// 15 wave-uniform float4 weight reads per c, 60 FMAs per c.
__global__ __launch_bounds__(256) void k_proj(const float* __restrict__ activ,
                                              float* __restrict__ ws) {
    const float* __restrict__ wt = ws + WT_OFF;
    float* __restrict__ S = ws + S_OFF;
    unsigned* smax = (unsigned*)(ws + SMAX_OFF);

    const int n = blockIdx.x * 256 + threadIdx.x;
    float acc[NPROJ];
#pragma unroll
    for (int d = 0; d < NPROJ; d++) acc[d] = 0.f;

    const float* fp = activ + n;
    float f = fp[0];  // prefetch c=0
#pragma unroll 1
    for (int c = 0; c < CDIM; c++) {
        // prefetch next channel's voxel value (hides HBM latency under the FMA burst)
        float fn = (c + 1 < CDIM) ? fp[(size_t)(c + 1) * NVOX] : 0.f;
        const float4* w4 = (const float4*)(wt + c * 64);
#pragma unroll
        for (int k = 0; k < 15; k++) {
            float4 w = w4[k];
            acc[4 * k + 0] = fmaf(w.x, f, acc[4 * k + 0]);
            acc[4 * k + 1] = fmaf(w.y, f, acc[4 * k + 1]);
            acc[4 * k + 2] = fmaf(w.z, f, acc[4 * k + 2]);
            acc[4 * k + 3] = fmaf(w.w, f, acc[4 * k + 3]);
        }
        f = fn;
    }

    // store projections (coalesced per d)
#pragma unroll
    for (int d = 0; d < NPROJ; d++) S[(size_t)d * NVOX + n] = acc[d];

    // block-level max of s (d<30), then deterministic global atomicMax
    __shared__ float wmax[NDIS][4];
    const int lane = threadIdx.x & 63, wid = threadIdx.x >> 6;
#pragma unroll
    for (int d = 0; d < NDIS; d++) {
        float m = acc[d];
#pragma unroll
        for (int off = 32; off > 0; off >>= 1) m = fmaxf(m, __shfl_xor(m, off));
        if (lane == 0) wmax[d][wid] = m;
    }
    __syncthreads();
    if (threadIdx.x < NDIS) {
        float m = fmaxf(fmaxf(wmax[threadIdx.x][0], wmax[threadIdx.x][1]),
                        fmaxf(wmax[threadIdx.x][2], wmax[threadIdx.x][3]));
        atomicMax(&smax[threadIdx.x], encf(m));
    }
}

// K2: softmax weights + weighted sums, per-wave partials (no float atomics -> deterministic).
__global__ __launch_bounds__(256) void k_soft(float* __restrict__ ws) {
    const float* __restrict__ S = ws + S_OFF;
    const unsigned* smax = (const unsigned*)(ws + SMAX_OFF);
    const float* invtau = ws + INVTAU_OFF;
    float* pnum = ws + PNUM_OFF;
    float* pden = ws + PDEN_OFF;

    const int n = blockIdx.x * 256 + threadIdx.x;
    const int lane = threadIdx.x & 63, wid = threadIdx.x >> 6;
    const int pidx = blockIdx.x * 4 + wid;  // [0, 4096)

#pragma unroll 1
    for (int d = 0; d < NDIS; d++) {
        float s = S[(size_t)d * NVOX + n];
        float h = S[(size_t)(d + NDIS) * NVOX + n];
        float x = (s - decf(smax[d])) * invtau[d];
        x = fminf(fmaxf(x, -60.f), 0.f);   // matches reference clip(-60, 0)
        float e = expf(x);
        float eh = e * h;
#pragma unroll
        for (int off = 32; off > 0; off >>= 1) {
            e  += __shfl_xor(e, off);
            eh += __shfl_xor(eh, off);
        }
        if (lane == 0) {
            pnum[d * 4096 + pidx] = eh;
            pden[d * 4096 + pidx] = e;
        }
    }
}

// K3: final reduce of 4096 partials per disease + head bias + NaN guard.
__global__ __launch_bounds__(256) void k_final(const float* __restrict__ ws,
                                               const float* __restrict__ head_b,
                                               float* __restrict__ out) {
    const int d = blockIdx.x;
    const float* pnum = ws + PNUM_OFF + d * 4096;
    const float* pden = ws + PDEN_OFF + d * 4096;
    float nu = 0.f, de = 0.f;
    for (int i = threadIdx.x; i < 4096; i += 256) { nu += pnum[i]; de += pden[i]; }
#pragma unroll
    for (int off = 32; off > 0; off >>= 1) {
        nu += __shfl_xor(nu, off);
        de += __shfl_xor(de, off);
    }
    __shared__ float sm[4][2];
    const int lane = threadIdx.x & 63, wid = threadIdx.x >> 6;
    if (lane == 0) { sm[wid][0] = nu; sm[wid][1] = de; }
    __syncthreads();
    if (threadIdx.x == 0) {
        float N = 0.f, D = 0.f;
        for (int w = 0; w < 4; w++) { N += sm[w][0]; D += sm[w][1]; }
        float o = N / fmaxf(D, 1e-12f) + head_b[d];
        if (o != o) o = 0.f;  // NaN guard (mirrors reference's where(isnan,0))
        out[d] = o;
    }
}

extern "C" void kernel_launch(void* const* d_in, const int* in_sizes, int n_in,
                              void* d_out, int out_size, void* d_ws, size_t ws_size,
                              hipStream_t stream) {
    const float* activ      = (const float*)d_in[0];
    const float* score_w    = (const float*)d_in[1];
    // d_in[2] = score_b — cancels exactly in the stable softmax, unused
    const float* head_w     = (const float*)d_in[3];
    const float* head_b     = (const float*)d_in[4];
    const float* temp_logit = (const float*)d_in[5];
    float* ws  = (float*)d_ws;
    float* out = (float*)d_out;

    k_prep <<<64,   256, 0, stream>>>(score_w, head_w, temp_logit, ws);
    k_proj <<<NBLK, 256, 0, stream>>>(activ, ws);
    k_soft <<<NBLK, 256, 0, stream>>>(ws);
    k_final<<<NDIS, 256, 0, stream>>>(ws, head_b, out);
}

// Round 2
// 686.192 us; speedup vs baseline: 1.1453x; 1.1453x over previous
//
#include <hip/hip_runtime.h>

// Problem constants
#define CDIM 1152
#define NDIS 30
#define NVOX (64*64*64)    // 262144 voxels
#define NBLK (NVOX/256)    // 1024 blocks of 256 threads, 1 voxel/thread

// Workspace layout (float offsets)
#define WT_OFF 0                        // W_t [1152][64]: rows 0..29 score_w, 30..59 head_w, 60..63 zero
#define PM_OFF (CDIM*64)                // [30][1024] per-block max of s
#define PD_OFF (PM_OFF + NDIS*NBLK)     // [30][1024] per-block sum of exp((s-mb)*invtau)
#define PN_OFF (PD_OFF + NDIS*NBLK)     // [30][1024] per-block sum of e*h

typedef float f32x4 __attribute__((ext_vector_type(4)));

__device__ inline float inv_tau(float t) {
    float sig = 1.f / (1.f + expf(-t));
    return 1.f / (0.2f + 1.8f * sig);
}

// K0: pack weights transposed [c][64] so the hot loop reads wave-uniform rows.
__global__ void k_prep(const float* __restrict__ score_w,
                       const float* __restrict__ head_w,
                       float* __restrict__ wt) {
    const int total = CDIM * 64;
    for (int i = blockIdx.x * blockDim.x + threadIdx.x; i < total; i += gridDim.x * blockDim.x) {
        int c = i >> 6, d = i & 63;
        float v = 0.f;
        if (d < NDIS)           v = score_w[d * CDIM + c];
        else if (d < 2 * NDIS)  v = head_w[(d - NDIS) * CDIM + c];
        wt[i] = v;
    }
}

// K1 (hot): thread owns voxel n. 60 f32 accumulators (15 f32x4).
// Weights: wave-uniform reads from a const __restrict__ arg -> s_load (lgkmcnt),
// keeping vmcnt exclusively for the depth-4 activ prefetch chain.
// Epilogue: per-block online-softmax partials (max, sum e, sum e*h) -> no S round-trip.
__global__ __launch_bounds__(256) void k_proj(const float* __restrict__ activ,
                                              const float* __restrict__ wt,
                                              const float* __restrict__ temp_logit,
                                              float* __restrict__ pm,
                                              float* __restrict__ pd,
                                              float* __restrict__ pn) {
    const int tid = threadIdx.x;
    const int n = blockIdx.x * 256 + tid;

    f32x4 A[15];
#pragma unroll
    for (int k = 0; k < 15; k++) A[k] = 0.f;

    const float* fp = activ + n;
    const f32x4* w4 = (const f32x4*)wt;

    // depth-4 prefetch
    float f0 = fp[(size_t)0 * NVOX];
    float f1 = fp[(size_t)1 * NVOX];
    float f2 = fp[(size_t)2 * NVOX];
    float f3 = fp[(size_t)3 * NVOX];

#define FMAROW(F, ROWPTR) \
    { _Pragma("unroll") for (int k = 0; k < 15; k++) A[k] += (ROWPTR)[k] * (F); }

#pragma unroll 1
    for (int c = 0; c < CDIM - 4; c += 4) {
        // issue next 4 activ loads (in flight across the 240 FMAs below)
        float g0 = fp[(size_t)(c + 4) * NVOX];
        float g1 = fp[(size_t)(c + 5) * NVOX];
        float g2 = fp[(size_t)(c + 6) * NVOX];
        float g3 = fp[(size_t)(c + 7) * NVOX];
        const f32x4* wr = w4 + (size_t)c * 16;
        FMAROW(f0, wr);
        FMAROW(f1, wr + 16);
        FMAROW(f2, wr + 32);
        FMAROW(f3, wr + 48);
        f0 = g0; f1 = g1; f2 = g2; f3 = g3;
    }
    {   // tail rows 1148..1151 (already prefetched)
        const f32x4* wr = w4 + (size_t)(CDIM - 4) * 16;
        FMAROW(f0, wr);
        FMAROW(f1, wr + 16);
        FMAROW(f2, wr + 32);
        FMAROW(f3, wr + 48);
    }
#undef FMAROW

    // ---- epilogue: per-block softmax partials ----
    float sv[NDIS], hv[NDIS];
#pragma unroll
    for (int d = 0; d < NDIS; d++) {
        sv[d] = A[d >> 2][d & 3];
        hv[d] = A[(d + NDIS) >> 2][(d + NDIS) & 3];
    }

    __shared__ float wmax[NDIS][4];
    __shared__ float wsum[NDIS][4];
    __shared__ float hsum[NDIS][4];
    const int lane = tid & 63, wid = tid >> 6;

    // phase 1: block max of s per disease
#pragma unroll
    for (int d = 0; d < NDIS; d++) {
        float m = sv[d];
#pragma unroll
        for (int off = 32; off > 0; off >>= 1) m = fmaxf(m, __shfl_xor(m, off));
        if (lane == 0) wmax[d][wid] = m;
    }
    __syncthreads();

    // phase 2: e = exp((s - mb) * invtau), sums of e and e*h
#pragma unroll 1
    for (int d = 0; d < NDIS; d++) {
        float4 mm = *(const float4*)wmax[d];
        float mb = fmaxf(fmaxf(mm.x, mm.y), fmaxf(mm.z, mm.w));
        float it = inv_tau(temp_logit[d]);
        float e = expf((sv[d] - mb) * it);
        float eh = e * hv[d];
#pragma unroll
        for (int off = 32; off > 0; off >>= 1) {
            e  += __shfl_xor(e, off);
            eh += __shfl_xor(eh, off);
        }
        if (lane == 0) { wsum[d][wid] = e; hsum[d][wid] = eh; }
    }
    __syncthreads();

    if (tid < NDIS) {
        float4 mm = *(const float4*)wmax[tid];
        float4 ee = *(const float4*)wsum[tid];
        float4 hh = *(const float4*)hsum[tid];
        pm[tid * NBLK + blockIdx.x] = fmaxf(fmaxf(mm.x, mm.y), fmaxf(mm.z, mm.w));
        pd[tid * NBLK + blockIdx.x] = (ee.x + ee.y) + (ee.z + ee.w);
        pn[tid * NBLK + blockIdx.x] = (hh.x + hh.y) + (hh.z + hh.w);
    }
}

// K2: combine 1024 per-block partials per disease with max-rescaling.
__global__ __launch_bounds__(256) void k_final(const float* __restrict__ pm,
                                               const float* __restrict__ pd,
                                               const float* __restrict__ pn,
                                               const float* __restrict__ temp_logit,
                                               const float* __restrict__ head_b,
                                               float* __restrict__ out) {
    const int d = blockIdx.x, tid = threadIdx.x;
    const int lane = tid & 63, wid = tid >> 6;
    const float* bm = pm + d * NBLK;
    const float* bd = pd + d * NBLK;
    const float* bn = pn + d * NBLK;

    float m0 = bm[tid], m1 = bm[tid + 256], m2 = bm[tid + 512], m3 = bm[tid + 768];
    float d0 = bd[tid], d1 = bd[tid + 256], d2 = bd[tid + 512], d3 = bd[tid + 768];
    float n0 = bn[tid], n1 = bn[tid + 256], n2 = bn[tid + 512], n3 = bn[tid + 768];

    __shared__ float sm[4], sd[4], sn[4];

    // global max M
    float mx = fmaxf(fmaxf(m0, m1), fmaxf(m2, m3));
#pragma unroll
    for (int off = 32; off > 0; off >>= 1) mx = fmaxf(mx, __shfl_xor(mx, off));
    if (lane == 0) sm[wid] = mx;
    __syncthreads();
    float M = fmaxf(fmaxf(sm[0], sm[1]), fmaxf(sm[2], sm[3]));

    float it = inv_tau(temp_logit[d]);
    float den = d0 * expf((m0 - M) * it) + d1 * expf((m1 - M) * it)
              + d2 * expf((m2 - M) * it) + d3 * expf((m3 - M) * it);
    float num = n0 * expf((m0 - M) * it) + n1 * expf((m1 - M) * it)
              + n2 * expf((m2 - M) * it) + n3 * expf((m3 - M) * it);
#pragma unroll
    for (int off = 32; off > 0; off >>= 1) {
        den += __shfl_xor(den, off);
        num += __shfl_xor(num, off);
    }
    __syncthreads();
    if (lane == 0) { sd[wid] = den; sn[wid] = num; }
    __syncthreads();
    if (tid == 0) {
        float D = (sd[0] + sd[1]) + (sd[2] + sd[3]);
        float N = (sn[0] + sn[1]) + (sn[2] + sn[3]);
        float o = N / fmaxf(D, 1e-12f) + head_b[d];
        if (o != o) o = 0.f;  // NaN guard (mirrors reference)
        out[d] = o;
    }
}

extern "C" void kernel_launch(void* const* d_in, const int* in_sizes, int n_in,
                              void* d_out, int out_size, void* d_ws, size_t ws_size,
                              hipStream_t stream) {
    const float* activ      = (const float*)d_in[0];
    const float* score_w    = (const float*)d_in[1];
    // d_in[2] = score_b — cancels exactly in the stable softmax, unused
    const float* head_w     = (const float*)d_in[3];
    const float* head_b     = (const float*)d_in[4];
    const float* temp_logit = (const float*)d_in[5];
    float* ws  = (float*)d_ws;
    float* out = (float*)d_out;

    k_prep <<<64,   256, 0, stream>>>(score_w, head_w, ws + WT_OFF);
    k_proj <<<NBLK, 256, 0, stream>>>(activ, ws + WT_OFF, temp_logit,
                                      ws + PM_OFF, ws + PD_OFF, ws + PN_OFF);
    k_final<<<NDIS, 256, 0, stream>>>(ws + PM_OFF, ws + PD_OFF, ws + PN_OFF,
                                      temp_logit, head_b, out);
}

// Round 3
// 273.103 us; speedup vs baseline: 2.8775x; 2.5126x over previous
//
#include <hip/hip_runtime.h>

// ---------------- problem constants ----------------
#define CDIM 1152
#define NDIS 30
#define NVOX (64*64*64)        // 262144 voxels
#define NT   128               // voxels per block
#define NBLK2 (NVOX/NT)        // 2048 blocks
#define KSTEPS (CDIM/32)       // 36 K-steps of 32 channels

// ---------------- workspace layout (float offsets) ----------------
// A-fragments: [t(36)][mt(4)][p(2)][lane(64)][e(8)] shorts = 147456 shorts = 73728 floats
#define AF_FLOATS 73728
#define PM_OFF AF_FLOATS                    // [30][2048] per-block max of s
#define PD_OFF (PM_OFF + NDIS*NBLK2)        // [30][2048] per-block sum e
#define PN_OFF (PD_OFF + NDIS*NBLK2)        // [30][2048] per-block sum e*h

typedef float f32x4 __attribute__((ext_vector_type(4)));
typedef short bf16x8 __attribute__((ext_vector_type(8)));

// RTNE f32 -> bf16 (bits), and back
__device__ inline short f2bf(float f) {
    unsigned u = __float_as_uint(f);
    unsigned r = (u + 0x7FFFu + ((u >> 16) & 1u)) >> 16;
    return (short)r;
}
__device__ inline float bf2f(short h) {
    return __uint_as_float(((unsigned)(unsigned short)h) << 16);
}
__device__ inline float inv_tau(float t) {
    float sig = 1.f / (1.f + expf(-t));
    return 1.f / (0.2f + 1.8f * sig);
}

// K0: precompute per-lane A-fragments (weights, bf16 hi/lo split).
// A-row m = lane&15 (m: 0..29 score_w, 30..59 head_w, 60..63 zero),
// k-slot map: k = 8*(lane>>4) + e  (same map used packing B -> consistency).
__global__ void k_prep(const float* __restrict__ score_w,
                       const float* __restrict__ head_w,
                       short* __restrict__ afrag) {
    int idx = blockIdx.x * 256 + threadIdx.x;      // 147456 total
    int e  = idx & 7;
    int l  = (idx >> 3) & 63;
    int p  = (idx >> 9) & 1;
    int mt = (idx >> 10) & 3;
    int t  = idx >> 12;
    if (t >= KSTEPS) return;
    int m = mt * 16 + (l & 15);
    int k = t * 32 + 8 * (l >> 4) + e;
    float w = 0.f;
    if (m < NDIS)          w = score_w[m * CDIM + k];
    else if (m < 2 * NDIS) w = head_w[(m - NDIS) * CDIM + k];
    short hi = f2bf(w);
    afrag[idx] = p ? f2bf(w - bf2f(hi)) : hi;
}

// K1 (hot): bf16-split MFMA projection + fused per-block softmax partials.
__global__ __launch_bounds__(256) void k_mfma(const float* __restrict__ activ,
                                              const short* __restrict__ afrag,
                                              const float* __restrict__ temp_logit,
                                              float* __restrict__ pm,
                                              float* __restrict__ pd,
                                              float* __restrict__ pn) {
    __shared__ float lds[2][32][NT];          // 32 KB staging, reused as [64][128] epilogue
    __shared__ float redm[32][8], rede[32][8], redh[32][8];

    const int tid  = threadIdx.x;
    const int lane = tid & 63;
    const int w    = tid >> 6;                // wave 0..3
    const int a    = lane >> 4;               // k-group 0..3
    const int i16  = lane & 15;
    const int nb   = blockIdx.x * NT;

    f32x4 acc[4][2];
#pragma unroll
    for (int mt = 0; mt < 4; mt++)
#pragma unroll
        for (int nt = 0; nt < 2; nt++) acc[mt][nt] = (f32x4)0.f;

    // stage K-step t's [32][128] f32 tile into buffer b via global_load_lds (width 16)
    auto stage = [&](int t, int b) {
        const int k0 = t * 32;
#pragma unroll
        for (int q = 0; q < 4; q++) {
            const int row = 8 * w + 2 * q;                       // wave-uniform
            const float* g = activ + (size_t)(k0 + row + (lane >> 5)) * NVOX
                           + nb + (lane & 31) * 4;               // per-lane global
            __builtin_amdgcn_global_load_lds(
                (const __attribute__((address_space(1))) unsigned int*)g,
                (__attribute__((address_space(3))) unsigned int*)&lds[b][row][0],
                16, 0, 0);
        }
    };

    stage(0, 0);
#pragma unroll 1
    for (int t = 0; t < KSTEPS; t++) {
        const int b = t & 1;
        __syncthreads();                      // vmcnt(0)+barrier: buf b fully staged
        if (t + 1 < KSTEPS) stage(t + 1, 1 - b);   // prefetch flies under compute

        // A fragments (L2-resident, 294 KB shared by all blocks)
        bf16x8 ah[4], al[4];
#pragma unroll
        for (int mt = 0; mt < 4; mt++) {
            ah[mt] = ((const bf16x8*)afrag)[((t * 4 + mt) * 2 + 0) * 64 + lane];
            al[mt] = ((const bf16x8*)afrag)[((t * 4 + mt) * 2 + 1) * 64 + lane];
        }

        // B fragments: read f32 from LDS, split to bf16 hi/lo in-register
        bf16x8 bh[2], bl[2];
#pragma unroll
        for (int nt = 0; nt < 2; nt++) {
            const int col = w * 32 + nt * 16 + i16;
#pragma unroll
            for (int e = 0; e < 8; e++) {
                float f = lds[b][8 * a + e][col];
                short hs = f2bf(f);                               // RTNE hi
                float lf = f - bf2f(hs);
                bh[nt][e] = hs;
                bl[nt][e] = (short)(__float_as_uint(lf) >> 16);   // trunc lo (enough)
            }
        }

        // 24 MFMA: (hi*hi + hi*lo + lo*hi)
#pragma unroll
        for (int mt = 0; mt < 4; mt++)
#pragma unroll
            for (int nt = 0; nt < 2; nt++) {
                acc[mt][nt] = __builtin_amdgcn_mfma_f32_16x16x32_bf16(ah[mt], bh[nt], acc[mt][nt], 0, 0, 0);
                acc[mt][nt] = __builtin_amdgcn_mfma_f32_16x16x32_bf16(ah[mt], bl[nt], acc[mt][nt], 0, 0, 0);
                acc[mt][nt] = __builtin_amdgcn_mfma_f32_16x16x32_bf16(al[mt], bh[nt], acc[mt][nt], 0, 0, 0);
            }
    }

    // ---- epilogue: dump D[64][128] to LDS, then block softmax partials ----
    __syncthreads();                          // everyone done reading staging LDS
    float* ep = (float*)lds;                  // [64 m][128 n]
#pragma unroll
    for (int mt = 0; mt < 4; mt++)
#pragma unroll
        for (int nt = 0; nt < 2; nt++)
#pragma unroll
            for (int r = 0; r < 4; r++) {
                int m = mt * 16 + a * 4 + r;  // verified C/D map: row=(lane>>4)*4+reg
                int n = w * 32 + nt * 16 + i16;
                ep[m * NT + n] = acc[mt][nt][r];
            }
    __syncthreads();

    const int d  = tid >> 3;                  // 0..31 (30 used)
    const int j8 = tid & 7;                   // 8 threads per disease
    if (d < NDIS) {
        float mx = -3.4e38f;
        for (int i = 0; i < 16; i++) mx = fmaxf(mx, ep[d * NT + j8 * 16 + i]);
        redm[d][j8] = mx;
    }
    __syncthreads();
    if (d < NDIS) {
        float mb = redm[d][0];
        for (int j = 1; j < 8; j++) mb = fmaxf(mb, redm[d][j]);
        float it = inv_tau(temp_logit[d]);
        float se = 0.f, sh = 0.f;
        for (int i = 0; i < 16; i++) {
            int ix = d * NT + j8 * 16 + i;
            float e = expf((ep[ix] - mb) * it);
            se += e;
            sh += e * ep[ix + NDIS * NT];
        }
        rede[d][j8] = se;
        redh[d][j8] = sh;
    }
    __syncthreads();
    if (tid < NDIS) {
        float mb = redm[tid][0];
        for (int j = 1; j < 8; j++) mb = fmaxf(mb, redm[tid][j]);
        float se = 0.f, sh = 0.f;
        for (int j = 0; j < 8; j++) { se += rede[tid][j]; sh += redh[tid][j]; }
        pm[tid * NBLK2 + blockIdx.x] = mb;
        pd[tid * NBLK2 + blockIdx.x] = se;
        pn[tid * NBLK2 + blockIdx.x] = sh;
    }
}

// K2: merge 2048 per-block partials per disease with max-rescaling.
__global__ __launch_bounds__(256) void k_final(const float* __restrict__ pm,
                                               const float* __restrict__ pd,
                                               const float* __restrict__ pn,
                                               const float* __restrict__ temp_logit,
                                               const float* __restrict__ head_b,
                                               float* __restrict__ out) {
    const int d = blockIdx.x, tid = threadIdx.x;
    const int lane = tid & 63, wid = tid >> 6;
    __shared__ float sm[4], sd[4], sn[4];
    const float* bm = pm + d * NBLK2;
    const float* bd = pd + d * NBLK2;
    const float* bn = pn + d * NBLK2;

    float m[8], e[8], h[8];
#pragma unroll
    for (int i = 0; i < 8; i++) {
        int ix = tid + i * 256;
        m[i] = bm[ix]; e[i] = bd[ix]; h[i] = bn[ix];
    }
    float mx = m[0];
#pragma unroll
    for (int i = 1; i < 8; i++) mx = fmaxf(mx, m[i]);
#pragma unroll
    for (int off = 32; off > 0; off >>= 1) mx = fmaxf(mx, __shfl_xor(mx, off));
    if (lane == 0) sm[wid] = mx;
    __syncthreads();
    float M = fmaxf(fmaxf(sm[0], sm[1]), fmaxf(sm[2], sm[3]));

    float it = inv_tau(temp_logit[d]);
    float den = 0.f, num = 0.f;
#pragma unroll
    for (int i = 0; i < 8; i++) {
        float sc = expf((m[i] - M) * it);
        den += e[i] * sc;
        num += h[i] * sc;
    }
#pragma unroll
    for (int off = 32; off > 0; off >>= 1) {
        den += __shfl_xor(den, off);
        num += __shfl_xor(num, off);
    }
    if (lane == 0) { sd[wid] = den; sn[wid] = num; }
    __syncthreads();
    if (tid == 0) {
        float D = (sd[0] + sd[1]) + (sd[2] + sd[3]);
        float N = (sn[0] + sn[1]) + (sn[2] + sn[3]);
        float o = N / fmaxf(D, 1e-12f) + head_b[d];
        if (o != o) o = 0.f;
        out[d] = o;
    }
}

extern "C" void kernel_launch(void* const* d_in, const int* in_sizes, int n_in,
                              void* d_out, int out_size, void* d_ws, size_t ws_size,
                              hipStream_t stream) {
    const float* activ      = (const float*)d_in[0];
    const float* score_w    = (const float*)d_in[1];
    // d_in[2] = score_b — cancels exactly in the stable softmax, unused
    const float* head_w     = (const float*)d_in[3];
    const float* head_b     = (const float*)d_in[4];
    const float* temp_logit = (const float*)d_in[5];
    float* ws  = (float*)d_ws;
    float* out = (float*)d_out;

    short* afrag = (short*)ws;
    k_prep <<<576,   256, 0, stream>>>(score_w, head_w, afrag);
    k_mfma <<<NBLK2, 256, 0, stream>>>(activ, afrag, temp_logit,
                                       ws + PM_OFF, ws + PD_OFF, ws + PN_OFF);
    k_final<<<NDIS,  256, 0, stream>>>(ws + PM_OFF, ws + PD_OFF, ws + PN_OFF,
                                       temp_logit, head_b, out);
}

// Round 4
// 250.553 us; speedup vs baseline: 3.1365x; 1.0900x over previous
//
#include <hip/hip_runtime.h>

// ---------------- problem constants ----------------
#define CDIM 1152
#define NDIS 30
#define NVOX (64*64*64)        // 262144 voxels
#define NT   128               // voxels per block
#define NBLK2 (NVOX/NT)        // 2048 blocks
#define KSTEPS (CDIM/32)       // 36 K-steps of 32 channels

// ---------------- workspace layout (float offsets) ----------------
// A-fragments: [t(36)][mt(4)][p(2)][lane(64)][e(8)] shorts = 147456 shorts = 73728 floats
#define AF_FLOATS 73728
#define PM_OFF AF_FLOATS                    // [30][2048] per-block max of s
#define PD_OFF (PM_OFF + NDIS*NBLK2)        // [30][2048] per-block sum e
#define PN_OFF (PD_OFF + NDIS*NBLK2)        // [30][2048] per-block sum e*h

typedef float f32x4 __attribute__((ext_vector_type(4)));
typedef short bf16x8 __attribute__((ext_vector_type(8)));

// RTNE f32 -> bf16 (bits), and back
__device__ inline short f2bf(float f) {
    unsigned u = __float_as_uint(f);
    unsigned r = (u + 0x7FFFu + ((u >> 16) & 1u)) >> 16;
    return (short)r;
}
__device__ inline float bf2f(short h) {
    return __uint_as_float(((unsigned)(unsigned short)h) << 16);
}
__device__ inline float inv_tau(float t) {
    float sig = 1.f / (1.f + expf(-t));
    return 1.f / (0.2f + 1.8f * sig);
}

// K0: precompute per-lane A-fragments (weights, bf16 hi/lo split).
// A-row m = lane&15 (m: 0..29 score_w, 30..59 head_w, 60..63 zero),
// k-slot map: k = 8*(lane>>4) + e  (same map used packing B -> consistency).
__global__ void k_prep(const float* __restrict__ score_w,
                       const float* __restrict__ head_w,
                       short* __restrict__ afrag) {
    int idx = blockIdx.x * 256 + threadIdx.x;      // 147456 total
    int e  = idx & 7;
    int l  = (idx >> 3) & 63;
    int p  = (idx >> 9) & 1;
    int mt = (idx >> 10) & 3;
    int t  = idx >> 12;
    if (t >= KSTEPS) return;
    int m = mt * 16 + (l & 15);
    int k = t * 32 + 8 * (l >> 4) + e;
    float w = 0.f;
    if (m < NDIS)          w = score_w[m * CDIM + k];
    else if (m < 2 * NDIS) w = head_w[(m - NDIS) * CDIM + k];
    short hi = f2bf(w);
    afrag[idx] = p ? f2bf(w - bf2f(hi)) : hi;
}

// K1 (hot): bf16-split MFMA projection + fused per-block softmax partials.
// ROUND-4 CHANGE: A-fragment loads are issued BEFORE the stage(t+1)
// global_load_lds ops (pinned by sched_barrier). vmcnt retires in issue
// order, so the MFMA's wait becomes vmcnt(4) — the 4 HBM prefetch loads
// stay in flight across the whole compute phase instead of being drained
// before the first MFMA (the round-3 order forced vmcnt(0)).
__global__ __launch_bounds__(256) void k_mfma(const float* __restrict__ activ,
                                              const short* __restrict__ afrag,
                                              const float* __restrict__ temp_logit,
                                              float* __restrict__ pm,
                                              float* __restrict__ pd,
                                              float* __restrict__ pn) {
    __shared__ float lds[2][32][NT];          // 32 KB staging, reused as [64][128] epilogue
    __shared__ float redm[32][8], rede[32][8], redh[32][8];

    const int tid  = threadIdx.x;
    const int lane = tid & 63;
    const int w    = tid >> 6;                // wave 0..3
    const int a    = lane >> 4;               // k-group 0..3
    const int i16  = lane & 15;
    const int nb   = blockIdx.x * NT;

    f32x4 acc[4][2];
#pragma unroll
    for (int mt = 0; mt < 4; mt++)
#pragma unroll
        for (int nt = 0; nt < 2; nt++) acc[mt][nt] = (f32x4)0.f;

    // stage K-step t's [32][128] f32 tile into buffer b via global_load_lds (width 16)
    auto stage = [&](int t, int b) {
        const int k0 = t * 32;
#pragma unroll
        for (int q = 0; q < 4; q++) {
            const int row = 8 * w + 2 * q;                       // wave-uniform
            const float* g = activ + (size_t)(k0 + row + (lane >> 5)) * NVOX
                           + nb + (lane & 31) * 4;               // per-lane global
            __builtin_amdgcn_global_load_lds(
                (const __attribute__((address_space(1))) unsigned int*)g,
                (__attribute__((address_space(3))) unsigned int*)&lds[b][row][0],
                16, 0, 0);
        }
    };

    stage(0, 0);
#pragma unroll 1
    for (int t = 0; t < KSTEPS; t++) {
        const int b = t & 1;
        __syncthreads();                      // vmcnt(0)+barrier: buf b fully staged

        // A fragments FIRST (L2-resident, issued before the HBM prefetch so
        // their vmcnt retires without draining it)
        bf16x8 ah[4], al[4];
#pragma unroll
        for (int mt = 0; mt < 4; mt++) {
            ah[mt] = ((const bf16x8*)afrag)[((t * 4 + mt) * 2 + 0) * 64 + lane];
            al[mt] = ((const bf16x8*)afrag)[((t * 4 + mt) * 2 + 1) * 64 + lane];
        }
        __builtin_amdgcn_sched_barrier(0);    // pin: A-loads issue before stage(t+1)

        if (t + 1 < KSTEPS) stage(t + 1, 1 - b);   // prefetch flies under compute

        // B fragments: read f32 from LDS, split to bf16 hi/lo in-register
        bf16x8 bh[2], bl[2];
#pragma unroll
        for (int nt = 0; nt < 2; nt++) {
            const int col = w * 32 + nt * 16 + i16;
#pragma unroll
            for (int e = 0; e < 8; e++) {
                float f = lds[b][8 * a + e][col];
                short hs = f2bf(f);                               // RTNE hi
                float lf = f - bf2f(hs);
                bh[nt][e] = hs;
                bl[nt][e] = (short)(__float_as_uint(lf) >> 16);   // trunc lo (enough)
            }
        }

        // 24 MFMA: (hi*hi + hi*lo + lo*hi)
#pragma unroll
        for (int mt = 0; mt < 4; mt++)
#pragma unroll
            for (int nt = 0; nt < 2; nt++) {
                acc[mt][nt] = __builtin_amdgcn_mfma_f32_16x16x32_bf16(ah[mt], bh[nt], acc[mt][nt], 0, 0, 0);
                acc[mt][nt] = __builtin_amdgcn_mfma_f32_16x16x32_bf16(ah[mt], bl[nt], acc[mt][nt], 0, 0, 0);
                acc[mt][nt] = __builtin_amdgcn_mfma_f32_16x16x32_bf16(al[mt], bh[nt], acc[mt][nt], 0, 0, 0);
            }
    }

    // ---- epilogue: dump D[64][128] to LDS, then block softmax partials ----
    __syncthreads();                          // everyone done reading staging LDS
    float* ep = (float*)lds;                  // [64 m][128 n]
#pragma unroll
    for (int mt = 0; mt < 4; mt++)
#pragma unroll
        for (int nt = 0; nt < 2; nt++)
#pragma unroll
            for (int r = 0; r < 4; r++) {
                int m = mt * 16 + a * 4 + r;  // verified C/D map: row=(lane>>4)*4+reg
                int n = w * 32 + nt * 16 + i16;
                ep[m * NT + n] = acc[mt][nt][r];
            }
    __syncthreads();

    const int d  = tid >> 3;                  // 0..31 (30 used)
    const int j8 = tid & 7;                   // 8 threads per disease
    if (d < NDIS) {
        float mx = -3.4e38f;
        for (int i = 0; i < 16; i++) mx = fmaxf(mx, ep[d * NT + j8 * 16 + i]);
        redm[d][j8] = mx;
    }
    __syncthreads();
    if (d < NDIS) {
        float mb = redm[d][0];
        for (int j = 1; j < 8; j++) mb = fmaxf(mb, redm[d][j]);
        float it = inv_tau(temp_logit[d]);
        float se = 0.f, sh = 0.f;
        for (int i = 0; i < 16; i++) {
            int ix = d * NT + j8 * 16 + i;
            float e = expf((ep[ix] - mb) * it);
            se += e;
            sh += e * ep[ix + NDIS * NT];
        }
        rede[d][j8] = se;
        redh[d][j8] = sh;
    }
    __syncthreads();
    if (tid < NDIS) {
        float mb = redm[tid][0];
        for (int j = 1; j < 8; j++) mb = fmaxf(mb, redm[tid][j]);
        float se = 0.f, sh = 0.f;
        for (int j = 0; j < 8; j++) { se += rede[tid][j]; sh += redh[tid][j]; }
        pm[tid * NBLK2 + blockIdx.x] = mb;
        pd[tid * NBLK2 + blockIdx.x] = se;
        pn[tid * NBLK2 + blockIdx.x] = sh;
    }
}

// K2: merge 2048 per-block partials per disease with max-rescaling.
__global__ __launch_bounds__(256) void k_final(const float* __restrict__ pm,
                                               const float* __restrict__ pd,
                                               const float* __restrict__ pn,
                                               const float* __restrict__ temp_logit,
                                               const float* __restrict__ head_b,
                                               float* __restrict__ out) {
    const int d = blockIdx.x, tid = threadIdx.x;
    const int lane = tid & 63, wid = tid >> 6;
    __shared__ float sm[4], sd[4], sn[4];
    const float* bm = pm + d * NBLK2;
    const float* bd = pd + d * NBLK2;
    const float* bn = pn + d * NBLK2;

    float m[8], e[8], h[8];
#pragma unroll
    for (int i = 0; i < 8; i++) {
        int ix = tid + i * 256;
        m[i] = bm[ix]; e[i] = bd[ix]; h[i] = bn[ix];
    }
    float mx = m[0];
#pragma unroll
    for (int i = 1; i < 8; i++) mx = fmaxf(mx, m[i]);
#pragma unroll
    for (int off = 32; off > 0; off >>= 1) mx = fmaxf(mx, __shfl_xor(mx, off));
    if (lane == 0) sm[wid] = mx;
    __syncthreads();
    float M = fmaxf(fmaxf(sm[0], sm[1]), fmaxf(sm[2], sm[3]));

    float it = inv_tau(temp_logit[d]);
    float den = 0.f, num = 0.f;
#pragma unroll
    for (int i = 0; i < 8; i++) {
        float sc = expf((m[i] - M) * it);
        den += e[i] * sc;
        num += h[i] * sc;
    }
#pragma unroll
    for (int off = 32; off > 0; off >>= 1) {
        den += __shfl_xor(den, off);
        num += __shfl_xor(num, off);
    }
    if (lane == 0) { sd[wid] = den; sn[wid] = num; }
    __syncthreads();
    if (tid == 0) {
        float D = (sd[0] + sd[1]) + (sd[2] + sd[3]);
        float N = (sn[0] + sn[1]) + (sn[2] + sn[3]);
        float o = N / fmaxf(D, 1e-12f) + head_b[d];
        if (o != o) o = 0.f;
        out[d] = o;
    }
}

extern "C" void kernel_launch(void* const* d_in, const int* in_sizes, int n_in,
                              void* d_out, int out_size, void* d_ws, size_t ws_size,
                              hipStream_t stream) {
    const float* activ      = (const float*)d_in[0];
    const float* score_w    = (const float*)d_in[1];
    // d_in[2] = score_b — cancels exactly in the stable softmax, unused
    const float* head_w     = (const float*)d_in[3];
    const float* head_b     = (const float*)d_in[4];
    const float* temp_logit = (const float*)d_in[5];
    float* ws  = (float*)d_ws;
    float* out = (float*)d_out;

    short* afrag = (short*)ws;
    k_prep <<<576,   256, 0, stream>>>(score_w, head_w, afrag);
    k_mfma <<<NBLK2, 256, 0, stream>>>(activ, afrag, temp_logit,
                                       ws + PM_OFF, ws + PD_OFF, ws + PN_OFF);
    k_final<<<NDIS,  256, 0, stream>>>(ws + PM_OFF, ws + PD_OFF, ws + PN_OFF,
                                       temp_logit, head_b, out);
}